// Round 4
// baseline (646.269 us; speedup 1.0000x reference)
//
#include <hip/hip_runtime.h>
#include <hip/hip_bf16.h>

// ---------------------------------------------------------------------------
// GCN: h = relu(GCNConv(x,W1,b1)); x1 = relu(GCNConv(h,W2,b2));
//      x2 = meanpool(x1,batch); out = log_softmax(relu(x2@fc1+b)@fc2+b)
//
// R4: XCD-sliced gather. x@W stored slice-major [8][N][F/8]; gather blocks
// pick slice = blockIdx%8 (round-robin XCD dispatch) so each XCD's gathered
// working set (3.2MB / 1.6MB) fits its 4MiB L2 (R3: 439MB L2-miss traffic).
// Edge record packed to 4B (row:17b | ew 15b fixed-point); rescale pass
// dropped (dinv[row] read from L2-hot table in-loop).
// ---------------------------------------------------------------------------

#define CAP 64
#define OVFCAP 8192

// pos = cnt[c]++; slot[c*CAP+pos] = row<<15 | q15(ew); overflow -> list+flag
__global__ void place_kernel(const int* __restrict__ rows, const int* __restrict__ cols,
                             const float* __restrict__ ew, int* __restrict__ cnt,
                             unsigned* __restrict__ slot, int4* __restrict__ ovf,
                             int* __restrict__ ovfcnt, int* __restrict__ flag, int E) {
    int e = blockIdx.x * 256 + threadIdx.x;
    if (e >= E) return;
    int r = rows[e], c = cols[e];
    int q = (int)(ew[e] * 32768.0f);
    if (q > 32767) q = 32767;
    int pos = atomicAdd(&cnt[c], 1);
    if (pos < CAP) {
        slot[(size_t)c * CAP + pos] = ((unsigned)r << 15) | (unsigned)q;
    } else {
        *flag = 1;
        int o = atomicAdd(ovfcnt, 1);
        if (o < OVFCAP) ovf[o] = make_int4(r, c, q, 0);
    }
}

// deg[i] = sum of quantized ew over bucket i (wave per node)
__global__ void degfin_kernel(const unsigned* __restrict__ slot, const int* __restrict__ cnt,
                              float* __restrict__ deg, int N) {
    const int w = threadIdx.x >> 6, lane = threadIdx.x & 63;
    const int i = blockIdx.x * 4 + w;
    if (i >= N) return;
    int m = cnt[i]; if (m > CAP) m = CAP;
    float v = 0.f;
    if (lane < m) v = (float)(slot[(size_t)i * CAP + lane] & 32767u) * (1.0f / 32768.0f);
    #pragma unroll
    for (int off = 1; off < 64; off <<= 1) v += __shfl_xor(v, off);
    if (lane == 0) deg[i] = v;
}

// overflow edges' weights into deg (normally ovfcnt==0 -> instant exit)
__global__ void ovfdeg_kernel(const int4* __restrict__ ovf, const int* __restrict__ ovfcnt,
                              float* __restrict__ deg) {
    int n = *ovfcnt; if (n > OVFCAP) n = OVFCAP;
    for (int k = threadIdx.x; k < n; k += 256)
        atomicAdd(&deg[ovf[k].y], (float)ovf[k].z * (1.0f / 32768.0f));
}

// dinv[i] = rsqrt(deg[i] + 1)   (self-loop weight 1)
__global__ void dinv_kernel(float* __restrict__ deg, int N) {
    int i = blockIdx.x * 256 + threadIdx.x;
    if (i < N) deg[i] = rsqrtf(deg[i] + 1.0f);
}

// out_sliced[slice][M][SW] = A[M][128] @ W[128][BN], slice width SW = BN/8.
template <int BN>
__global__ void gemm_kernel(const float* __restrict__ A, const float* __restrict__ W,
                            float* __restrict__ out, int M) {
    constexpr int K = 128;
    constexpr int BK = 32;
    constexpr int SW = BN / 8;
    constexpr int CG = BN / 4;
    constexpr int RG = 256 / CG;
    constexpr int BM = RG * 4;
    __shared__ float xs[BM][BK + 4];
    __shared__ float ws[BK][BN];
    const int t = threadIdx.x;
    const int cg = t % CG, rg = t / CG;
    const int c0 = cg * 4, r0 = rg * 4;
    const int rowBase = blockIdx.x * BM;
    float acc[4][4] = {};
    for (int k0 = 0; k0 < K; k0 += BK) {
        constexpr int XL = BM * BK / (256 * 4);
        #pragma unroll
        for (int i = 0; i < XL; ++i) {
            int f = (t + i * 256) * 4;
            int rr = f / BK, kk = f % BK;
            int grow = rowBase + rr;
            float4 v = (grow < M) ? *(const float4*)&A[(size_t)grow * K + k0 + kk]
                                  : make_float4(0.f, 0.f, 0.f, 0.f);
            *(float4*)&xs[rr][kk] = v;
        }
        constexpr int WL = BK * BN / (256 * 4);
        #pragma unroll
        for (int i = 0; i < WL; ++i) {
            int f = (t + i * 256) * 4;
            int kk = f / BN, cc = f % BN;
            *(float4*)&ws[kk][cc] = *(const float4*)&W[(size_t)(k0 + kk) * BN + cc];
        }
        __syncthreads();
        #pragma unroll
        for (int kk = 0; kk < BK; ++kk) {
            float4 wv = *(float4*)&ws[kk][c0];
            float xv[4];
            #pragma unroll
            for (int i = 0; i < 4; ++i) xv[i] = xs[r0 + i][kk];
            #pragma unroll
            for (int i = 0; i < 4; ++i) {
                acc[i][0] += xv[i] * wv.x;
                acc[i][1] += xv[i] * wv.y;
                acc[i][2] += xv[i] * wv.z;
                acc[i][3] += xv[i] * wv.w;
            }
        }
        __syncthreads();
    }
    const int slice = c0 / SW, cw = c0 % SW;
    float* dst0 = out + (size_t)slice * M * SW + cw;
    #pragma unroll
    for (int i = 0; i < 4; ++i) {
        int grow = rowBase + r0 + i;
        if (grow < M)
            *(float4*)&dst0[(size_t)grow * SW] =
                make_float4(acc[i][0], acc[i][1], acc[i][2], acc[i][3]);
    }
}

// Sliced aggregation: slice = blockIdx%8 -> XCD-local 1/8 feature sub-table.
// Wave per node; LG lanes per edge (float4 each), EPW edges in flight.
// flag==0: fused epilogue relu(dinv*acc + xw*dinv^2 + b). flag==1: raw S-sum.
template <int F>
__global__ void gather_kernel(const float* __restrict__ xsb, const unsigned* __restrict__ slot,
                              const int* __restrict__ cnt, const float* __restrict__ dinv,
                              const float* __restrict__ b, const int* __restrict__ flag,
                              float* __restrict__ out, int N) {
    constexpr int SW = F / 8;
    constexpr int LG = SW / 4;       // lanes per edge
    constexpr int EPW = 64 / LG;     // edges in flight per wave
    const int slice = blockIdx.x & 7;
    const int grp = blockIdx.x >> 3;
    const int w = threadIdx.x >> 6, lane = threadIdx.x & 63;
    const int i = grp * 4 + w;
    if (i >= N) return;
    const int sub = lane / LG, cg = lane % LG;
    const float* xs = xsb + (size_t)slice * N * SW;
    int m = cnt[i]; if (m > CAP) m = CAP;
    const unsigned* bkt = slot + (size_t)i * CAP;
    float4 acc = make_float4(0.f, 0.f, 0.f, 0.f);
    int j = sub;
    for (; j + EPW < m; j += 2 * EPW) {
        unsigned u0 = bkt[j], u1 = bkt[j + EPW];
        int r0 = u0 >> 15, r1 = u1 >> 15;
        float c0 = (float)(u0 & 32767u) * (1.0f / 32768.0f) * dinv[r0];
        float c1 = (float)(u1 & 32767u) * (1.0f / 32768.0f) * dinv[r1];
        float4 v0 = *(const float4*)&xs[(size_t)r0 * SW + cg * 4];
        float4 v1 = *(const float4*)&xs[(size_t)r1 * SW + cg * 4];
        acc.x += v0.x * c0 + v1.x * c1;
        acc.y += v0.y * c0 + v1.y * c1;
        acc.z += v0.z * c0 + v1.z * c1;
        acc.w += v0.w * c0 + v1.w * c1;
    }
    if (j < m) {
        unsigned u = bkt[j];
        int r = u >> 15;
        float c = (float)(u & 32767u) * (1.0f / 32768.0f) * dinv[r];
        float4 v = *(const float4*)&xs[(size_t)r * SW + cg * 4];
        acc.x += v.x * c; acc.y += v.y * c; acc.z += v.z * c; acc.w += v.w * c;
    }
    #pragma unroll
    for (int off = LG; off < 64; off <<= 1) {
        acc.x += __shfl_xor(acc.x, off);
        acc.y += __shfl_xor(acc.y, off);
        acc.z += __shfl_xor(acc.z, off);
        acc.w += __shfl_xor(acc.w, off);
    }
    if (sub == 0) {
        float4* dst = (float4*)&out[(size_t)i * F + slice * SW + cg * 4];
        if (*flag == 0) {
            float d = dinv[i], d2 = d * d;
            float4 xv = *(const float4*)&xs[(size_t)i * SW + cg * 4];
            float4 bb = *(const float4*)&b[slice * SW + cg * 4];
            float4 o;
            o.x = fmaxf(acc.x * d + xv.x * d2 + bb.x, 0.f);
            o.y = fmaxf(acc.y * d + xv.y * d2 + bb.y, 0.f);
            o.z = fmaxf(acc.z * d + xv.z * d2 + bb.z, 0.f);
            o.w = fmaxf(acc.w * d + xv.w * d2 + bb.w, 0.f);
            *dst = o;
        } else {
            *dst = acc;   // raw S-sum; ovfmsg + epi kernels finish
        }
    }
}

// flag==1 only: add overflow-edge messages (S-space) via atomics (sliced xw)
template <int F>
__global__ void ovfmsg_kernel(const float* __restrict__ xsb, const int4* __restrict__ ovf,
                              const int* __restrict__ ovfcnt, const float* __restrict__ dinv,
                              const int* __restrict__ flag, float* __restrict__ out, int N) {
    constexpr int SW = F / 8;
    if (*flag == 0) return;
    int n = *ovfcnt; if (n > OVFCAP) n = OVFCAP;
    int total = n * (F / 4);
    for (int g = blockIdx.x * 256 + threadIdx.x; g < total; g += gridDim.x * 256) {
        int k = g / (F / 4), q = g % (F / 4);
        int4 rec = ovf[k];
        float coef = (float)rec.z * (1.0f / 32768.0f) * dinv[rec.x];
        int col = q * 4, slice = col / SW, cw = col % SW;
        float4 v = *(const float4*)&xsb[(size_t)slice * N * SW + (size_t)rec.x * SW + cw];
        float* dst = &out[(size_t)rec.y * F + col];
        atomicAdd(dst + 0, v.x * coef);
        atomicAdd(dst + 1, v.y * coef);
        atomicAdd(dst + 2, v.z * coef);
        atomicAdd(dst + 3, v.w * coef);
    }
}

// flag==1 only: epilogue relu(dinv*S + xw*dinv^2 + b) (sliced xw)
template <int F>
__global__ void epi_kernel(float* __restrict__ out, const float* __restrict__ xsb,
                           const float* __restrict__ dinv, const float* __restrict__ b,
                           const int* __restrict__ flag, int N) {
    constexpr int SW = F / 8;
    if (*flag == 0) return;
    int g = blockIdx.x * 256 + threadIdx.x;
    int n = g / (F / 4), q = g % (F / 4);
    if (n >= N) return;
    float d = dinv[n], d2 = d * d;
    int col = q * 4, slice = col / SW, cw = col % SW;
    float4 a = ((const float4*)out)[g];
    float4 xv = *(const float4*)&xsb[(size_t)slice * N * SW + (size_t)n * SW + cw];
    float4 bb = *(const float4*)&b[col];
    float4 o;
    o.x = fmaxf(a.x * d + xv.x * d2 + bb.x, 0.f);
    o.y = fmaxf(a.y * d + xv.y * d2 + bb.y, 0.f);
    o.z = fmaxf(a.z * d + xv.z * d2 + bb.z, 0.f);
    o.w = fmaxf(a.w * d + xv.w * d2 + bb.w, 0.f);
    ((float4*)out)[g] = o;
}

// sums[batch[n]] += x1[n]; cnt[batch[n]] += 1 (sorted batch, boundary atomics)
__global__ void pool_kernel(const float* __restrict__ x1, const int* __restrict__ batch,
                            float* __restrict__ sums, float* __restrict__ cnt, int N) {
    constexpr int QG = 16, S = 16, ITER = 16;
    int t = threadIdx.x;
    int q = t % QG, s = t / QG;
    int n0 = blockIdx.x * (S * ITER) + s * ITER;
    float4 acc = make_float4(0.f, 0.f, 0.f, 0.f);
    float cacc = 0.f;
    int gcur = -1;
    for (int i = 0; i < ITER; ++i) {
        int n = n0 + i;
        if (n >= N) break;
        int gid = batch[n];
        if (gid != gcur) {
            if (gcur >= 0) {
                float* dst = &sums[gcur * 64 + q * 4];
                atomicAdd(dst + 0, acc.x);
                atomicAdd(dst + 1, acc.y);
                atomicAdd(dst + 2, acc.z);
                atomicAdd(dst + 3, acc.w);
                if (q == 0) atomicAdd(&cnt[gcur], cacc);
            }
            gcur = gid;
            acc = make_float4(0.f, 0.f, 0.f, 0.f);
            cacc = 0.f;
        }
        float4 a = ((const float4*)x1)[n * QG + q];
        acc.x += a.x; acc.y += a.y; acc.z += a.z; acc.w += a.w;
        if (q == 0) cacc += 1.f;
    }
    if (gcur >= 0) {
        float* dst = &sums[gcur * 64 + q * 4];
        atomicAdd(dst + 0, acc.x);
        atomicAdd(dst + 1, acc.y);
        atomicAdd(dst + 2, acc.z);
        atomicAdd(dst + 3, acc.w);
        if (q == 0) atomicAdd(&cnt[gcur], cacc);
    }
}

// Final MLP head + log_softmax, one block. G=64 graphs.
__global__ void head_kernel(const float* __restrict__ sums, const float* __restrict__ cnt,
                            const float* __restrict__ fc1W, const float* __restrict__ fc1b,
                            const float* __restrict__ fc2W, const float* __restrict__ fc2b,
                            float* __restrict__ out) {
    __shared__ float x2[64 * 64];
    __shared__ float h[64 * 128];
    __shared__ float logits[64 * 2];
    int t = threadIdx.x;
    for (int i = t; i < 64 * 64; i += 256) {
        int g = i / 64;
        x2[i] = sums[i] / fmaxf(cnt[g], 1.f);
    }
    __syncthreads();
    for (int i = t; i < 64 * 128; i += 256) {
        int g = i / 128, k = i % 128;
        float a = fc1b[k];
        #pragma unroll 8
        for (int j = 0; j < 64; ++j) a += x2[g * 64 + j] * fc1W[j * 128 + k];
        h[i] = fmaxf(a, 0.f);
    }
    __syncthreads();
    if (t < 128) {
        int g = t / 2, m = t % 2;
        float a = fc2b[m];
        #pragma unroll 8
        for (int k = 0; k < 128; ++k) a += h[g * 128 + k] * fc2W[k * 2 + m];
        logits[t] = a;
    }
    __syncthreads();
    if (t < 128) {
        int g = t / 2, m = t % 2;
        float l0 = logits[g * 2 + 0], l1 = logits[g * 2 + 1];
        float mx = fmaxf(l0, l1);
        float lse = mx + logf(expf(l0 - mx) + expf(l1 - mx));
        out[t] = (m == 0 ? l0 : l1) - lse;
    }
}

extern "C" void kernel_launch(void* const* d_in, const int* in_sizes, int n_in,
                              void* d_out, int out_size, void* d_ws, size_t ws_size,
                              hipStream_t stream) {
    const float* x      = (const float*)d_in[0];
    const int*   eidx   = (const int*)d_in[1];
    const float* ew     = (const float*)d_in[2];
    const int*   batch  = (const int*)d_in[3];
    const float* W1     = (const float*)d_in[4];
    const float* b1     = (const float*)d_in[5];
    const float* W2     = (const float*)d_in[6];
    const float* b2     = (const float*)d_in[7];
    const float* fc1W   = (const float*)d_in[8];
    const float* fc1b   = (const float*)d_in[9];
    const float* fc2W   = (const float*)d_in[10];
    const float* fc2b   = (const float*)d_in[11];
    float* out = (float*)d_out;

    const int N = in_sizes[3];          // 50000 nodes
    const int E = in_sizes[2];          // 1600000 edges
    const int* rows = eidx;
    const int* cols = eidx + E;

    float* ws = (float*)d_ws;
    size_t off = 0;
    auto alloc = [&](size_t n) { float* p = ws + off; off += (n + 15) & ~(size_t)15; return p; };
    // --- zero-initialized region ---
    int*      cnt    = (int*)alloc(N);
    float*    sums   = alloc(64 * 64);
    float*    cntf   = alloc(16);
    int*      ovfcnt = (int*)alloc(16);
    int*      flag   = (int*)alloc(16);
    size_t zfloats = off;
    // --- rest ---
    float*    deg    = alloc(N);
    unsigned* slot   = (unsigned*)alloc((size_t)N * CAP);
    int4*     ovf    = (int4*)alloc((size_t)OVFCAP * 4);
    float*    bufA   = alloc((size_t)N * 128);   // xw1s; later xw2s (lo) + x1 (hi)
    float*    bufB   = alloc((size_t)N * 128);   // h
    float* xw1s = bufA;
    float* h    = bufB;
    float* xw2s = bufA;
    float* x1   = bufA + (size_t)N * 64;
    (void)ws_size;

    hipMemsetAsync(d_ws, 0, zfloats * sizeof(float), stream);

    // CSR build: bucket (packed 4B records) -> per-bucket degree -> dinv
    place_kernel<<<(E + 255) / 256, 256, 0, stream>>>(rows, cols, ew, cnt, slot, ovf, ovfcnt, flag, E);
    degfin_kernel<<<(N + 3) / 4, 256, 0, stream>>>(slot, cnt, deg, N);
    ovfdeg_kernel<<<1, 256, 0, stream>>>(ovf, ovfcnt, deg);
    dinv_kernel<<<(N + 255) / 256, 256, 0, stream>>>(deg, N);

    // Layer 1 (sliced xw1)
    gemm_kernel<128><<<(N + 31) / 32, 256, 0, stream>>>(x, W1, xw1s, N);
    gather_kernel<128><<<((N + 3) / 4) * 8, 256, 0, stream>>>(xw1s, slot, cnt, deg, b1, flag, h, N);
    ovfmsg_kernel<128><<<64, 256, 0, stream>>>(xw1s, ovf, ovfcnt, deg, flag, h, N);
    epi_kernel<128><<<(N * 32 + 255) / 256, 256, 0, stream>>>(h, xw1s, deg, b1, flag, N);

    // Layer 2 (sliced xw2)
    gemm_kernel<64><<<(N + 63) / 64, 256, 0, stream>>>(h, W2, xw2s, N);
    gather_kernel<64><<<((N + 3) / 4) * 8, 256, 0, stream>>>(xw2s, slot, cnt, deg, b2, flag, x1, N);
    ovfmsg_kernel<64><<<64, 256, 0, stream>>>(xw2s, ovf, ovfcnt, deg, flag, x1, N);
    epi_kernel<64><<<(N * 16 + 255) / 256, 256, 0, stream>>>(x1, xw2s, deg, b2, flag, N);

    // Mean-pool + head
    pool_kernel<<<(N + 255) / 256, 256, 0, stream>>>(x1, batch, sums, cntf, N);
    head_kernel<<<1, 256, 0, stream>>>(sums, cntf, fc1W, fc1b, fc2W, fc2b, out);
}

// Round 5
// 470.677 us; speedup vs baseline: 1.3731x; 1.3731x over previous
//
#include <hip/hip_runtime.h>
#include <hip/hip_bf16.h>

// ---------------------------------------------------------------------------
// GCN: h = relu(GCNConv(x,W1,b1)); x1 = relu(GCNConv(h,W2,b2));
//      x2 = meanpool(x1,batch); out = log_softmax(relu(x2@fc1+b)@fc2+b)
//
// R5: keep R4's XCD-sliced gather (FETCH 439->100MB confirmed) but fix its
// overhead: (1) dinv[row]*2^-15 folded into the x@W table by the GEMM
// epilogue -- no in-loop dinv gather (was 12.8M random loads), cheap unpack;
// (2) 4 nodes per wave (4 lanes/edge, 4 edges in flight/node) -- 4x fewer
// waves, 2-step reduction; (3) layer-2 uses 4 slices so SW=16 keeps full
// 64B-line utilization.
// ---------------------------------------------------------------------------

#define CAP 64
#define OVFCAP 8192

// pos = cnt[c]++; slot[c*CAP+pos] = row<<15 | q15(ew); overflow -> list+flag
__global__ void place_kernel(const int* __restrict__ rows, const int* __restrict__ cols,
                             const float* __restrict__ ew, int* __restrict__ cnt,
                             unsigned* __restrict__ slot, int4* __restrict__ ovf,
                             int* __restrict__ ovfcnt, int* __restrict__ flag, int E) {
    int e = blockIdx.x * 256 + threadIdx.x;
    if (e >= E) return;
    int r = rows[e], c = cols[e];
    int q = (int)(ew[e] * 32768.0f);
    if (q > 32767) q = 32767;
    int pos = atomicAdd(&cnt[c], 1);
    if (pos < CAP) {
        slot[(size_t)c * CAP + pos] = ((unsigned)r << 15) | (unsigned)q;
    } else {
        *flag = 1;
        int o = atomicAdd(ovfcnt, 1);
        if (o < OVFCAP) ovf[o] = make_int4(r, c, q, 0);
    }
}

// deg[i] = sum of quantized ew over bucket i (wave per node)
__global__ void degfin_kernel(const unsigned* __restrict__ slot, const int* __restrict__ cnt,
                              float* __restrict__ deg, int N) {
    const int w = threadIdx.x >> 6, lane = threadIdx.x & 63;
    const int i = blockIdx.x * 4 + w;
    if (i >= N) return;
    int m = cnt[i]; if (m > CAP) m = CAP;
    float v = 0.f;
    if (lane < m) v = (float)(slot[(size_t)i * CAP + lane] & 32767u) * (1.0f / 32768.0f);
    #pragma unroll
    for (int off = 1; off < 64; off <<= 1) v += __shfl_xor(v, off);
    if (lane == 0) deg[i] = v;
}

// overflow edges' weights into deg (normally ovfcnt==0 -> instant exit)
__global__ void ovfdeg_kernel(const int4* __restrict__ ovf, const int* __restrict__ ovfcnt,
                              float* __restrict__ deg) {
    int n = *ovfcnt; if (n > OVFCAP) n = OVFCAP;
    for (int k = threadIdx.x; k < n; k += 256)
        atomicAdd(&deg[ovf[k].y], (float)ovf[k].z * (1.0f / 32768.0f));
}

// dinv[i] = rsqrt(deg[i] + 1)   (self-loop weight 1)
__global__ void dinv_kernel(float* __restrict__ deg, int N) {
    int i = blockIdx.x * 256 + threadIdx.x;
    if (i < N) deg[i] = rsqrtf(deg[i] + 1.0f);
}

// out_sliced[slice][M][SW] = (A[M][128] @ W[128][BN]) * dinv[row] * 2^-15.
// The dinv*2^-15 prescale is consumed by gather (coef = raw int q15) and
// undone (*d*32768) for the self-loop term.
template <int BN, int S>
__global__ void gemm_kernel(const float* __restrict__ A, const float* __restrict__ W,
                            const float* __restrict__ dinv, float* __restrict__ out, int M) {
    constexpr int K = 128;
    constexpr int BK = 32;
    constexpr int SW = BN / S;
    constexpr int CG = BN / 4;
    constexpr int RG = 256 / CG;
    constexpr int BM = RG * 4;
    __shared__ float xs[BM][BK + 4];
    __shared__ float ws[BK][BN];
    const int t = threadIdx.x;
    const int cg = t % CG, rg = t / CG;
    const int c0 = cg * 4, r0 = rg * 4;
    const int rowBase = blockIdx.x * BM;
    float acc[4][4] = {};
    for (int k0 = 0; k0 < K; k0 += BK) {
        constexpr int XL = BM * BK / (256 * 4);
        #pragma unroll
        for (int i = 0; i < XL; ++i) {
            int f = (t + i * 256) * 4;
            int rr = f / BK, kk = f % BK;
            int grow = rowBase + rr;
            float4 v = (grow < M) ? *(const float4*)&A[(size_t)grow * K + k0 + kk]
                                  : make_float4(0.f, 0.f, 0.f, 0.f);
            *(float4*)&xs[rr][kk] = v;
        }
        constexpr int WL = BK * BN / (256 * 4);
        #pragma unroll
        for (int i = 0; i < WL; ++i) {
            int f = (t + i * 256) * 4;
            int kk = f / BN, cc = f % BN;
            *(float4*)&ws[kk][cc] = *(const float4*)&W[(size_t)(k0 + kk) * BN + cc];
        }
        __syncthreads();
        #pragma unroll
        for (int kk = 0; kk < BK; ++kk) {
            float4 wv = *(float4*)&ws[kk][c0];
            float xv[4];
            #pragma unroll
            for (int i = 0; i < 4; ++i) xv[i] = xs[r0 + i][kk];
            #pragma unroll
            for (int i = 0; i < 4; ++i) {
                acc[i][0] += xv[i] * wv.x;
                acc[i][1] += xv[i] * wv.y;
                acc[i][2] += xv[i] * wv.z;
                acc[i][3] += xv[i] * wv.w;
            }
        }
        __syncthreads();
    }
    const int slice = c0 / SW, cw = c0 % SW;
    float* dst0 = out + (size_t)slice * M * SW + cw;
    #pragma unroll
    for (int i = 0; i < 4; ++i) {
        int grow = rowBase + r0 + i;
        if (grow < M) {
            float s = dinv[grow] * (1.0f / 32768.0f);
            *(float4*)&dst0[(size_t)grow * SW] =
                make_float4(acc[i][0] * s, acc[i][1] * s, acc[i][2] * s, acc[i][3] * s);
        }
    }
}

// Sliced aggregation. slice = blockIdx%S -> XCD-local sub-table (SW=16 floats,
// full 64B line per edge). Wave handles 4 nodes: lane = nd*16 + e*4 + cg
// (nd=node, e=edge-in-flight, cg=float4 chunk). Table is prescaled by
// dinv[row]*2^-15 so coef = (float)q15 raw. flag==0: fused epilogue
// relu(d*acc + xs_self*(d*32768) + b). flag==1: raw S-sum (fixups follow).
template <int F, int S>
__global__ void gather_kernel(const float* __restrict__ xsb, const unsigned* __restrict__ slot,
                              const int* __restrict__ cnt, const float* __restrict__ dinv,
                              const float* __restrict__ b, const int* __restrict__ flag,
                              float* __restrict__ out, int N) {
    constexpr int SW = F / S;        // 16
    constexpr int LG = SW / 4;       // 4 lanes per edge
    constexpr int EPN = 4;           // edges in flight per node
    constexpr int NPW = 64 / (LG * EPN);  // 4 nodes per wave
    const int slice = blockIdx.x % S;
    const int grp = blockIdx.x / S;
    const int w = threadIdx.x >> 6, lane = threadIdx.x & 63;
    const int cg = lane % LG;
    const int e  = (lane / LG) % EPN;
    const int nd = lane / (LG * EPN);
    const int i = (grp * 4 + w) * NPW + nd;
    const bool iv = (i < N);
    const int ic = iv ? i : 0;
    const float4* xs4 = (const float4*)(xsb + (size_t)slice * N * SW);
    int m = iv ? cnt[ic] : 0; if (m > CAP) m = CAP;
    const unsigned* bkt = slot + (size_t)ic * CAP;
    float4 acc = make_float4(0.f, 0.f, 0.f, 0.f);
    int j = e;
    for (; j + EPN < m; j += 2 * EPN) {
        unsigned u0 = bkt[j], u1 = bkt[j + EPN];
        int r0 = u0 >> 15, r1 = u1 >> 15;
        float c0 = (float)(u0 & 32767u);
        float c1 = (float)(u1 & 32767u);
        float4 v0 = xs4[r0 * LG + cg];
        float4 v1 = xs4[r1 * LG + cg];
        acc.x += v0.x * c0 + v1.x * c1;
        acc.y += v0.y * c0 + v1.y * c1;
        acc.z += v0.z * c0 + v1.z * c1;
        acc.w += v0.w * c0 + v1.w * c1;
    }
    if (j < m) {
        unsigned u = bkt[j];
        int r = u >> 15;
        float c = (float)(u & 32767u);
        float4 v = xs4[r * LG + cg];
        acc.x += v.x * c; acc.y += v.y * c; acc.z += v.z * c; acc.w += v.w * c;
    }
    // reduce over e (EPN=4): two butterfly steps
    acc.x += __shfl_xor(acc.x, LG);     acc.y += __shfl_xor(acc.y, LG);
    acc.z += __shfl_xor(acc.z, LG);     acc.w += __shfl_xor(acc.w, LG);
    acc.x += __shfl_xor(acc.x, 2 * LG); acc.y += __shfl_xor(acc.y, 2 * LG);
    acc.z += __shfl_xor(acc.z, 2 * LG); acc.w += __shfl_xor(acc.w, 2 * LG);
    if (e == 0 && iv) {
        float4* dst = (float4*)&out[(size_t)i * F + slice * SW + cg * 4];
        if (*flag == 0) {
            float d = dinv[i];
            float sd = d * 32768.0f;
            float4 xv = xs4[i * LG + cg];
            float4 bb = *(const float4*)&b[slice * SW + cg * 4];
            float4 o;
            o.x = fmaxf(acc.x * d + xv.x * sd + bb.x, 0.f);
            o.y = fmaxf(acc.y * d + xv.y * sd + bb.y, 0.f);
            o.z = fmaxf(acc.z * d + xv.z * sd + bb.z, 0.f);
            o.w = fmaxf(acc.w * d + xv.w * sd + bb.w, 0.f);
            *dst = o;
        } else {
            *dst = acc;   // raw S-sum; ovfmsg + epi kernels finish
        }
    }
}

// flag==1 only: add overflow-edge messages (S-space). Table prescaled, so
// message = (float)q15 * xs_scaled[row].
template <int F, int S>
__global__ void ovfmsg_kernel(const float* __restrict__ xsb, const int4* __restrict__ ovf,
                              const int* __restrict__ ovfcnt, const int* __restrict__ flag,
                              float* __restrict__ out, int N) {
    constexpr int SW = F / S;
    if (*flag == 0) return;
    int n = *ovfcnt; if (n > OVFCAP) n = OVFCAP;
    int total = n * (F / 4);
    for (int g = blockIdx.x * 256 + threadIdx.x; g < total; g += gridDim.x * 256) {
        int k = g / (F / 4), q = g % (F / 4);
        int4 rec = ovf[k];
        float coef = (float)rec.z;
        int col = q * 4, slice = col / SW, cw = col % SW;
        float4 v = *(const float4*)&xsb[(size_t)slice * N * SW + (size_t)rec.x * SW + cw];
        float* dst = &out[(size_t)rec.y * F + col];
        atomicAdd(dst + 0, v.x * coef);
        atomicAdd(dst + 1, v.y * coef);
        atomicAdd(dst + 2, v.z * coef);
        atomicAdd(dst + 3, v.w * coef);
    }
}

// flag==1 only: epilogue relu(d*S + xs_scaled*(d*32768) + b)
template <int F, int S>
__global__ void epi_kernel(float* __restrict__ out, const float* __restrict__ xsb,
                           const float* __restrict__ dinv, const float* __restrict__ b,
                           const int* __restrict__ flag, int N) {
    constexpr int SW = F / S;
    if (*flag == 0) return;
    int g = blockIdx.x * 256 + threadIdx.x;
    int n = g / (F / 4), q = g % (F / 4);
    if (n >= N) return;
    float d = dinv[n], sd = d * 32768.0f;
    int col = q * 4, slice = col / SW, cw = col % SW;
    float4 a = ((const float4*)out)[g];
    float4 xv = *(const float4*)&xsb[(size_t)slice * N * SW + (size_t)n * SW + cw];
    float4 bb = *(const float4*)&b[col];
    float4 o;
    o.x = fmaxf(a.x * d + xv.x * sd + bb.x, 0.f);
    o.y = fmaxf(a.y * d + xv.y * sd + bb.y, 0.f);
    o.z = fmaxf(a.z * d + xv.z * sd + bb.z, 0.f);
    o.w = fmaxf(a.w * d + xv.w * sd + bb.w, 0.f);
    ((float4*)out)[g] = o;
}

// sums[batch[n]] += x1[n]; cnt[batch[n]] += 1 (sorted batch, boundary atomics)
__global__ void pool_kernel(const float* __restrict__ x1, const int* __restrict__ batch,
                            float* __restrict__ sums, float* __restrict__ cnt, int N) {
    constexpr int QG = 16, S = 16, ITER = 16;
    int t = threadIdx.x;
    int q = t % QG, s = t / QG;
    int n0 = blockIdx.x * (S * ITER) + s * ITER;
    float4 acc = make_float4(0.f, 0.f, 0.f, 0.f);
    float cacc = 0.f;
    int gcur = -1;
    for (int i = 0; i < ITER; ++i) {
        int n = n0 + i;
        if (n >= N) break;
        int gid = batch[n];
        if (gid != gcur) {
            if (gcur >= 0) {
                float* dst = &sums[gcur * 64 + q * 4];
                atomicAdd(dst + 0, acc.x);
                atomicAdd(dst + 1, acc.y);
                atomicAdd(dst + 2, acc.z);
                atomicAdd(dst + 3, acc.w);
                if (q == 0) atomicAdd(&cnt[gcur], cacc);
            }
            gcur = gid;
            acc = make_float4(0.f, 0.f, 0.f, 0.f);
            cacc = 0.f;
        }
        float4 a = ((const float4*)x1)[n * QG + q];
        acc.x += a.x; acc.y += a.y; acc.z += a.z; acc.w += a.w;
        if (q == 0) cacc += 1.f;
    }
    if (gcur >= 0) {
        float* dst = &sums[gcur * 64 + q * 4];
        atomicAdd(dst + 0, acc.x);
        atomicAdd(dst + 1, acc.y);
        atomicAdd(dst + 2, acc.z);
        atomicAdd(dst + 3, acc.w);
        if (q == 0) atomicAdd(&cnt[gcur], cacc);
    }
}

// Final MLP head + log_softmax, one block. G=64 graphs.
__global__ void head_kernel(const float* __restrict__ sums, const float* __restrict__ cnt,
                            const float* __restrict__ fc1W, const float* __restrict__ fc1b,
                            const float* __restrict__ fc2W, const float* __restrict__ fc2b,
                            float* __restrict__ out) {
    __shared__ float x2[64 * 64];
    __shared__ float h[64 * 128];
    __shared__ float logits[64 * 2];
    int t = threadIdx.x;
    for (int i = t; i < 64 * 64; i += 256) {
        int g = i / 64;
        x2[i] = sums[i] / fmaxf(cnt[g], 1.f);
    }
    __syncthreads();
    for (int i = t; i < 64 * 128; i += 256) {
        int g = i / 128, k = i % 128;
        float a = fc1b[k];
        #pragma unroll 8
        for (int j = 0; j < 64; ++j) a += x2[g * 64 + j] * fc1W[j * 128 + k];
        h[i] = fmaxf(a, 0.f);
    }
    __syncthreads();
    if (t < 128) {
        int g = t / 2, m = t % 2;
        float a = fc2b[m];
        #pragma unroll 8
        for (int k = 0; k < 128; ++k) a += h[g * 128 + k] * fc2W[k * 2 + m];
        logits[t] = a;
    }
    __syncthreads();
    if (t < 128) {
        int g = t / 2, m = t % 2;
        float l0 = logits[g * 2 + 0], l1 = logits[g * 2 + 1];
        float mx = fmaxf(l0, l1);
        float lse = mx + logf(expf(l0 - mx) + expf(l1 - mx));
        out[t] = (m == 0 ? l0 : l1) - lse;
    }
}

extern "C" void kernel_launch(void* const* d_in, const int* in_sizes, int n_in,
                              void* d_out, int out_size, void* d_ws, size_t ws_size,
                              hipStream_t stream) {
    const float* x      = (const float*)d_in[0];
    const int*   eidx   = (const int*)d_in[1];
    const float* ew     = (const float*)d_in[2];
    const int*   batch  = (const int*)d_in[3];
    const float* W1     = (const float*)d_in[4];
    const float* b1     = (const float*)d_in[5];
    const float* W2     = (const float*)d_in[6];
    const float* b2     = (const float*)d_in[7];
    const float* fc1W   = (const float*)d_in[8];
    const float* fc1b   = (const float*)d_in[9];
    const float* fc2W   = (const float*)d_in[10];
    const float* fc2b   = (const float*)d_in[11];
    float* out = (float*)d_out;

    const int N = in_sizes[3];          // 50000 nodes
    const int E = in_sizes[2];          // 1600000 edges
    const int* rows = eidx;
    const int* cols = eidx + E;

    float* ws = (float*)d_ws;
    size_t off = 0;
    auto alloc = [&](size_t n) { float* p = ws + off; off += (n + 15) & ~(size_t)15; return p; };
    // --- zero-initialized region ---
    int*      cnt    = (int*)alloc(N);
    float*    sums   = alloc(64 * 64);
    float*    cntf   = alloc(16);
    int*      ovfcnt = (int*)alloc(16);
    int*      flag   = (int*)alloc(16);
    size_t zfloats = off;
    // --- rest ---
    float*    deg    = alloc(N);
    unsigned* slot   = (unsigned*)alloc((size_t)N * CAP);
    int4*     ovf    = (int4*)alloc((size_t)OVFCAP * 4);
    float*    bufA   = alloc((size_t)N * 128);   // xw1s; later xw2s (lo) + x1 (hi)
    float*    bufB   = alloc((size_t)N * 128);   // h
    float* xw1s = bufA;
    float* h    = bufB;
    float* xw2s = bufA;
    float* x1   = bufA + (size_t)N * 64;
    (void)ws_size;

    hipMemsetAsync(d_ws, 0, zfloats * sizeof(float), stream);

    // CSR build: bucket (packed 4B records) -> per-bucket degree -> dinv
    place_kernel<<<(E + 255) / 256, 256, 0, stream>>>(rows, cols, ew, cnt, slot, ovf, ovfcnt, flag, E);
    degfin_kernel<<<(N + 3) / 4, 256, 0, stream>>>(slot, cnt, deg, N);
    ovfdeg_kernel<<<1, 256, 0, stream>>>(ovf, ovfcnt, deg);
    dinv_kernel<<<(N + 255) / 256, 256, 0, stream>>>(deg, N);

    // Layer 1: 8 slices (per-XCD working set 3.2MB)
    gemm_kernel<128, 8><<<(N + 31) / 32, 256, 0, stream>>>(x, W1, deg, xw1s, N);
    gather_kernel<128, 8><<<((N + 15) / 16) * 8, 256, 0, stream>>>(xw1s, slot, cnt, deg, b1, flag, h, N);
    ovfmsg_kernel<128, 8><<<64, 256, 0, stream>>>(xw1s, ovf, ovfcnt, flag, h, N);
    epi_kernel<128, 8><<<(N * 32 + 255) / 256, 256, 0, stream>>>(h, xw1s, deg, b1, flag, N);

    // Layer 2: 4 slices (SW stays 16 -> full line utilization)
    gemm_kernel<64, 4><<<(N + 63) / 64, 256, 0, stream>>>(h, W2, deg, xw2s, N);
    gather_kernel<64, 4><<<((N + 15) / 16) * 4, 256, 0, stream>>>(xw2s, slot, cnt, deg, b2, flag, x1, N);
    ovfmsg_kernel<64, 4><<<64, 256, 0, stream>>>(xw2s, ovf, ovfcnt, flag, x1, N);
    epi_kernel<64, 4><<<(N * 16 + 255) / 256, 256, 0, stream>>>(x1, xw2s, deg, b2, flag, N);

    // Mean-pool + head
    pool_kernel<<<(N + 255) / 256, 256, 0, stream>>>(x1, batch, sums, cntf, N);
    head_kernel<<<1, 256, 0, stream>>>(sums, cntf, fc1W, fc1b, fc2W, fc2b, out);
}